// Round 8
// baseline (814.232 us; speedup 1.0000x reference)
//
#include <hip/hip_runtime.h>

#define W 128
#define ROWS 64      // dst rows per block in fused_conv
#define BSHIFT 10    // 1024 dst ids per bucket
#define BSZ 1024
// LDS union: mins = 4 ch * 64 rows * 32 lanes dwords (32 KB); h = 64 rows * 264 shorts (33792 B)
#define SMEM_DW 8448
#define MINS(c, r, l) smem[((c) << 11) + ((r) << 5) + (l)]

typedef short bf16x8 __attribute__((ext_vector_type(8)));
typedef float f32x4 __attribute__((ext_vector_type(4)));

__device__ __forceinline__ float lrelu(float x) { return x > 0.f ? x : 0.01f * x; }

__device__ __forceinline__ unsigned short f2bf(float f) {
    unsigned u = __float_as_uint(f);
    u += 0x7fffu + ((u >> 16) & 1u);
    return (unsigned short)(u >> 16);
}
__device__ __forceinline__ float bfu(unsigned short u) {
    return __uint_as_float(((unsigned)u) << 16);
}
__device__ __forceinline__ float4 bf4_to_f4(ushort4 u) {
    return make_float4(bfu(u.x), bfu(u.y), bfu(u.z), bfu(u.w));
}
__device__ __forceinline__ ushort4 f4_to_bf4(float4 f) {
    return make_ushort4(f2bf(f.x), f2bf(f.y), f2bf(f.z), f2bf(f.w));
}
// monotonic uint encoding of float (order-preserving): min(enc) == enc(min)
__device__ __forceinline__ unsigned enc_f(float f) {
    unsigned b = __float_as_uint(f);
    return (b & 0x80000000u) ? ~b : (b | 0x80000000u);
}
__device__ __forceinline__ float dec_f(unsigned e) {
    unsigned b = (e & 0x80000000u) ? (e ^ 0x80000000u) : ~e;
    return __uint_as_float(b);
}

// ---- initial embed: lrelu(in @ Wm + b) -> bf16 ----
template <int K>
__global__ void embed_kernel(const float* __restrict__ in, const float* __restrict__ Wm,
                             const float* __restrict__ bias, unsigned short* __restrict__ outb,
                             int n) {
    int t = blockIdx.x * 256 + threadIdx.x;
    int row = t >> 7, c = t & 127;
    if (row >= n) return;
    float s = bias[c];
#pragma unroll
    for (int k = 0; k < K; k++) s += in[row * K + k] * Wm[k * W + c];
    outb[(size_t)row * W + c] = f2bf(lrelu(s));
}

// ---- fused weight convert: 4x [256][128] fp32 -> [128][256] bf16 transposed ----
__global__ void wconv4_kernel(const float* __restrict__ W0, const float* __restrict__ W1,
                              const float* __restrict__ W2, const float* __restrict__ W3,
                              unsigned short* __restrict__ T0, unsigned short* __restrict__ T1,
                              unsigned short* __restrict__ T2, unsigned short* __restrict__ T3) {
    int which = blockIdx.x >> 7;
    const float* Wm = (which == 0) ? W0 : (which == 1) ? W1 : (which == 2) ? W2 : W3;
    unsigned short* Wt = (which == 0) ? T0 : (which == 1) ? T1 : (which == 2) ? T2 : T3;
    int i = (blockIdx.x & 127) * 256 + threadIdx.x;
    int k = i >> 7, n = i & 127;
    Wt[n * 256 + k] = f2bf(Wm[k * W + n]);
}

// ---- bucket-partitioned CSR build over concatenated dst domain ----
struct PairSrc {
    const int* d0; const int* s0; int n0;
    const int* d1; const int* s1; int n1;
    const int* d2; const int* s2; int n2;
    int NE, NF;
};

__device__ __forceinline__ void pair_at(const PairSrc& P, int g, int& dp, int& sp) {
    dp = -1; sp = 0;
    if (g < P.n0) { dp = P.d0[g]; sp = P.s0[g]; }
    else if (g < P.n0 + P.n1) { int j = g - P.n0; dp = P.NE + P.d1[j]; sp = P.s1[j]; }
    else if (g < P.n0 + P.n1 + P.n2) { int j = g - P.n0 - P.n1; dp = P.NE + P.NF + P.d2[j]; sp = P.s2[j]; }
}

#define CHUNK 4096

__global__ __launch_bounds__(256) void part_hist(PairSrc P, int* __restrict__ gcnt) {
    __shared__ int hist[512];
    int t = threadIdx.x;
    for (int j = t; j < 512; j += 256) hist[j] = 0;
    __syncthreads();
    int g0 = blockIdx.x * CHUNK;
#pragma unroll
    for (int k = 0; k < 16; k++) {
        int dp, sp;
        pair_at(P, g0 + k * 256 + t, dp, sp);
        if (dp >= 0) atomicAdd(&hist[dp >> BSHIFT], 1);
    }
    __syncthreads();
    for (int j = t; j < 512; j += 256)
        if (hist[j]) atomicAdd(&gcnt[j], hist[j]);
}

__global__ void bucket_scan(const int* __restrict__ gcnt, int* __restrict__ goff,
                            int* __restrict__ gcur, int NB, int NP) {
    __shared__ int s[512];
    int t = threadIdx.x;
    int v = (t < NB) ? gcnt[t] : 0;
    s[t] = v;
    __syncthreads();
    for (int off = 1; off < 512; off <<= 1) {
        int add = (t >= off) ? s[t - off] : 0;
        __syncthreads();
        s[t] += add;
        __syncthreads();
    }
    if (t < NB) {
        int excl = s[t] - v;
        goff[t] = excl;
        gcur[t] = excl;
    }
    if (t == 0) goff[NB] = NP;
}

__global__ __launch_bounds__(256) void part_scatter(PairSrc P, int* __restrict__ gcur,
                                                    int2* __restrict__ pairs) {
    __shared__ int hist[512];
    __shared__ int base[512];
    int t = threadIdx.x;
    for (int j = t; j < 512; j += 256) hist[j] = 0;
    __syncthreads();
    int g0 = blockIdx.x * CHUNK;
    int dv[16], sv[16], rk[16];
#pragma unroll
    for (int k = 0; k < 16; k++) {
        pair_at(P, g0 + k * 256 + t, dv[k], sv[k]);
        rk[k] = (dv[k] >= 0) ? atomicAdd(&hist[dv[k] >> BSHIFT], 1) : 0;
    }
    __syncthreads();
    for (int j = t; j < 512; j += 256)
        base[j] = hist[j] ? atomicAdd(&gcur[j], hist[j]) : 0;
    __syncthreads();
#pragma unroll
    for (int k = 0; k < 16; k++) {
        if (dv[k] >= 0) pairs[base[dv[k] >> BSHIFT] + rk[k]] = make_int2(dv[k], sv[k]);
    }
}

// one block per bucket: LDS counting sort -> rowptr + cp (src,dst) pairs
__global__ __launch_bounds__(256) void bucket_sort(const int2* __restrict__ pairs,
                                                   const int* __restrict__ goff, int D, int NP,
                                                   int* __restrict__ rowptr,
                                                   int2* __restrict__ cp) {
    __shared__ int hist[BSZ];
    __shared__ int base[BSZ];
    __shared__ int tsum[256];
    int b = blockIdx.x, t = threadIdx.x;
    int d0 = b << BSHIFT;
    int roff = goff[b], rend = goff[b + 1], cnt = rend - roff;
    for (int j = t; j < BSZ; j += 256) hist[j] = 0;
    __syncthreads();
    for (int i = t; i < cnt; i += 256) {
        int2 pr = pairs[roff + i];
        atomicAdd(&hist[pr.x - d0], 1);
    }
    __syncthreads();
    int loc[4], s0 = 0;
#pragma unroll
    for (int k = 0; k < 4; k++) {
        loc[k] = s0;
        s0 += hist[t * 4 + k];
    }
    tsum[t] = s0;
    __syncthreads();
    for (int off = 1; off < 256; off <<= 1) {
        int add = (t >= off) ? tsum[t - off] : 0;
        __syncthreads();
        tsum[t] += add;
        __syncthreads();
    }
    int ebase = tsum[t] - s0;
#pragma unroll
    for (int k = 0; k < 4; k++) base[t * 4 + k] = ebase + loc[k];
    __syncthreads();
    for (int j = t; j < BSZ; j += 256) {
        int d = d0 + j;
        if (d < D) rowptr[d] = roff + base[j];
    }
    if (b == 0 && t == 0) rowptr[D] = NP;
    for (int j = t; j < BSZ; j += 256) hist[j] = base[j];
    __syncthreads();
    for (int i = t; i < cnt; i += 256) {
        int2 pr = pairs[roff + i];
        int pos = roff + atomicAdd(&hist[pr.x - d0], 1);
        cp[pos] = make_int2(pr.y, pr.x);  // (src, dst)
    }
}

// =====================================================================
// fused conv, edge-parallel gather, 64 rows/block, 4 waves, VGPR cap 128
// =====================================================================
template <bool OUT_F32>
__global__ __launch_bounds__(256, 4) void fused_conv_ep(
    const unsigned short* __restrict__ xsb, const unsigned short* __restrict__ xdb,
    unsigned short* __restrict__ out_b, float* __restrict__ out_f,
    const int* __restrict__ rowptr, const int2* __restrict__ cp, int dstoff,
    const unsigned short* __restrict__ Wt, const float* __restrict__ bias, int n_dst) {
    __shared__ unsigned smem[SMEM_DW];
    int t = threadIdx.x;
    int wave = t >> 6, lane = t & 63;
    int li = lane & 31, halfIdx = t >> 5;  // 0..7
    int r0 = blockIdx.x * ROWS;

    for (int j = t; j < 8192; j += 256) smem[j] = 0xFFFFFFFFu;

    int rbase = halfIdx * 8;  // 8 rows per half
    ushort4 xdu[8];
    int degv[8];
#pragma unroll
    for (int rr = 0; rr < 8; rr++) {
        int d = r0 + rbase + rr;
        xdu[rr] = make_ushort4(0, 0, 0, 0);
        degv[rr] = 0;
        if (d < n_dst) {
            xdu[rr] = ((const ushort4*)xdb)[(size_t)d * 32 + li];
            degv[rr] = rowptr[d + 1] - rowptr[d];
        }
    }
    __syncthreads();

    // --- phase B: edge-parallel gather-min (independent loads, bank-clean atomics)
    int rEnd = (r0 + ROWS < n_dst) ? r0 + ROWS : n_dst;
    int prBeg = rowptr[r0], prEnd = rowptr[rEnd];
    const ushort4* xs4 = (const ushort4*)xsb;
    int dbase = dstoff + r0;
    int p = prBeg + halfIdx;
    while (p + 24 < prEnd) {
        int2 c0 = cp[p], c1 = cp[p + 8], c2 = cp[p + 16], c3 = cp[p + 24];
        ushort4 v0 = xs4[(size_t)c0.x * 32 + li];
        ushort4 v1 = xs4[(size_t)c1.x * 32 + li];
        ushort4 v2 = xs4[(size_t)c2.x * 32 + li];
        ushort4 v3 = xs4[(size_t)c3.x * 32 + li];
        int d0 = c0.y - dbase, d1 = c1.y - dbase, d2 = c2.y - dbase, d3 = c3.y - dbase;
        float4 f0 = bf4_to_f4(v0), f1 = bf4_to_f4(v1), f2 = bf4_to_f4(v2), f3 = bf4_to_f4(v3);
        atomicMin(&MINS(0, d0, li), enc_f(f0.x)); atomicMin(&MINS(1, d0, li), enc_f(f0.y));
        atomicMin(&MINS(2, d0, li), enc_f(f0.z)); atomicMin(&MINS(3, d0, li), enc_f(f0.w));
        atomicMin(&MINS(0, d1, li), enc_f(f1.x)); atomicMin(&MINS(1, d1, li), enc_f(f1.y));
        atomicMin(&MINS(2, d1, li), enc_f(f1.z)); atomicMin(&MINS(3, d1, li), enc_f(f1.w));
        atomicMin(&MINS(0, d2, li), enc_f(f2.x)); atomicMin(&MINS(1, d2, li), enc_f(f2.y));
        atomicMin(&MINS(2, d2, li), enc_f(f2.z)); atomicMin(&MINS(3, d2, li), enc_f(f2.w));
        atomicMin(&MINS(0, d3, li), enc_f(f3.x)); atomicMin(&MINS(1, d3, li), enc_f(f3.y));
        atomicMin(&MINS(2, d3, li), enc_f(f3.z)); atomicMin(&MINS(3, d3, li), enc_f(f3.w));
        p += 32;
    }
    while (p < prEnd) {
        int2 c0 = cp[p];
        float4 f = bf4_to_f4(xs4[(size_t)c0.x * 32 + li]);
        int dl = c0.y - dbase;
        atomicMin(&MINS(0, dl, li), enc_f(f.x)); atomicMin(&MINS(1, dl, li), enc_f(f.y));
        atomicMin(&MINS(2, dl, li), enc_f(f.z)); atomicMin(&MINS(3, dl, li), enc_f(f.w));
        p += 8;
    }
    __syncthreads();

    // --- phase C: mins -> mx, then rewrite smem as bf16 h tile
    float4 mxv[8];
#pragma unroll
    for (int rr = 0; rr < 8; rr++) {
        int r = rbase + rr;
        unsigned m0 = MINS(0, r, li), m1 = MINS(1, r, li);
        unsigned m2 = MINS(2, r, li), m3 = MINS(3, r, li);
        float4 xdv = bf4_to_f4(xdu[rr]);
        mxv[rr].x = degv[rr] ? (xdv.x - dec_f(m0)) : 0.f;
        mxv[rr].y = degv[rr] ? (xdv.y - dec_f(m1)) : 0.f;
        mxv[rr].z = degv[rr] ? (xdv.z - dec_f(m2)) : 0.f;
        mxv[rr].w = degv[rr] ? (xdv.w - dec_f(m3)) : 0.f;
    }
    __syncthreads();
    unsigned short* h = (unsigned short*)smem;  // row stride 264 shorts
#pragma unroll
    for (int rr = 0; rr < 8; rr++) {
        int r = rbase + rr;
        *(ushort4*)&h[r * 264 + 4 * li] = xdu[rr];
        *(ushort4*)&h[r * 264 + 128 + 4 * li] = f4_to_bf4(mxv[rr]);
    }
    __syncthreads();

    // --- phase D: MFMA. wave -> 16-row tile, all 8 col-tiles (64 MFMA/wave)
    int rt = wave;
    int m = lane & 15, q = lane >> 4;
    f32x4 acc[8];
#pragma unroll
    for (int ct = 0; ct < 8; ct++) acc[ct] = (f32x4){0.f, 0.f, 0.f, 0.f};
    for (int k0 = 0; k0 < 256; k0 += 32) {
        bf16x8 a = *(const bf16x8*)&h[(rt * 16 + m) * 264 + k0 + q * 8];
#pragma unroll
        for (int ct = 0; ct < 8; ct++) {
            bf16x8 b = *(const bf16x8*)&Wt[(ct * 16 + m) * 256 + k0 + q * 8];
            acc[ct] = __builtin_amdgcn_mfma_f32_16x16x32_bf16(a, b, acc[ct], 0, 0, 0);
        }
    }
#pragma unroll
    for (int ct = 0; ct < 8; ct++) {
        int col = ct * 16 + m;
        float bc = bias[col];
#pragma unroll
        for (int reg = 0; reg < 4; reg++) {
            int r_l = rt * 16 + q * 4 + reg;
            int row = r0 + r_l;
            if (row < n_dst) {
                float xold = bfu(h[r_l * 264 + col]);
                float val = xold + lrelu(acc[ct][reg] + bc);
                if (OUT_F32) out_f[(size_t)row * W + col] = val;
                else out_b[(size_t)row * W + col] = f2bf(val);
            }
        }
    }
}

// ---- v2e variant: src row = on-the-fly vertex embed (12 B loads) ----
__global__ __launch_bounds__(256, 4) void fused_conv_v2e_ep(
    const float* __restrict__ verts, const float* __restrict__ Wv, const float* __restrict__ bv,
    unsigned short* __restrict__ x_eb, const int* __restrict__ rowptr,
    const int2* __restrict__ cp, const unsigned short* __restrict__ Wt,
    const float* __restrict__ bias, int n_dst) {
    __shared__ unsigned smem[SMEM_DW];
    int t = threadIdx.x;
    int wave = t >> 6, lane = t & 63;
    int li = lane & 31, halfIdx = t >> 5;
    int r0 = blockIdx.x * ROWS;

    for (int j = t; j < 8192; j += 256) smem[j] = 0xFFFFFFFFu;

    float4 wv0 = *(const float4*)&Wv[0 * W + 4 * li];
    float4 wv1 = *(const float4*)&Wv[1 * W + 4 * li];
    float4 wv2 = *(const float4*)&Wv[2 * W + 4 * li];
    float4 bvv = *(const float4*)&bv[4 * li];

    int rbase = halfIdx * 8;
    ushort4 xdu[8];
    int degv[8];
#pragma unroll
    for (int rr = 0; rr < 8; rr++) {
        int d = r0 + rbase + rr;
        xdu[rr] = make_ushort4(0, 0, 0, 0);
        degv[rr] = 0;
        if (d < n_dst) {
            xdu[rr] = ((const ushort4*)x_eb)[(size_t)d * 32 + li];
            degv[rr] = rowptr[d + 1] - rowptr[d];
        }
    }
    __syncthreads();

    int rEnd = (r0 + ROWS < n_dst) ? r0 + ROWS : n_dst;
    int prBeg = rowptr[r0], prEnd = rowptr[rEnd];
    int dbase = r0;
    int p = prBeg + halfIdx;
    while (p + 24 < prEnd) {
        int2 c0 = cp[p], c1 = cp[p + 8], c2 = cp[p + 16], c3 = cp[p + 24];
        float a00 = verts[3 * c0.x], a01 = verts[3 * c0.x + 1], a02 = verts[3 * c0.x + 2];
        float a10 = verts[3 * c1.x], a11 = verts[3 * c1.x + 1], a12 = verts[3 * c1.x + 2];
        float a20 = verts[3 * c2.x], a21 = verts[3 * c2.x + 1], a22 = verts[3 * c2.x + 2];
        float a30 = verts[3 * c3.x], a31 = verts[3 * c3.x + 1], a32 = verts[3 * c3.x + 2];
        int d0 = c0.y - dbase, d1 = c1.y - dbase, d2 = c2.y - dbase, d3 = c3.y - dbase;
        float4 e0, e1, e2, e3;
        e0.x = lrelu(bvv.x + a00 * wv0.x + a01 * wv1.x + a02 * wv2.x);
        e0.y = lrelu(bvv.y + a00 * wv0.y + a01 * wv1.y + a02 * wv2.y);
        e0.z = lrelu(bvv.z + a00 * wv0.z + a01 * wv1.z + a02 * wv2.z);
        e0.w = lrelu(bvv.w + a00 * wv0.w + a01 * wv1.w + a02 * wv2.w);
        e1.x = lrelu(bvv.x + a10 * wv0.x + a11 * wv1.x + a12 * wv2.x);
        e1.y = lrelu(bvv.y + a10 * wv0.y + a11 * wv1.y + a12 * wv2.y);
        e1.z = lrelu(bvv.z + a10 * wv0.z + a11 * wv1.z + a12 * wv2.z);
        e1.w = lrelu(bvv.w + a10 * wv0.w + a11 * wv1.w + a12 * wv2.w);
        e2.x = lrelu(bvv.x + a20 * wv0.x + a21 * wv1.x + a22 * wv2.x);
        e2.y = lrelu(bvv.y + a20 * wv0.y + a21 * wv1.y + a22 * wv2.y);
        e2.z = lrelu(bvv.z + a20 * wv0.z + a21 * wv1.z + a22 * wv2.z);
        e2.w = lrelu(bvv.w + a20 * wv0.w + a21 * wv1.w + a22 * wv2.w);
        e3.x = lrelu(bvv.x + a30 * wv0.x + a31 * wv1.x + a32 * wv2.x);
        e3.y = lrelu(bvv.y + a30 * wv0.y + a31 * wv1.y + a32 * wv2.y);
        e3.z = lrelu(bvv.z + a30 * wv0.z + a31 * wv1.z + a32 * wv2.z);
        e3.w = lrelu(bvv.w + a30 * wv0.w + a31 * wv1.w + a32 * wv2.w);
        atomicMin(&MINS(0, d0, li), enc_f(e0.x)); atomicMin(&MINS(1, d0, li), enc_f(e0.y));
        atomicMin(&MINS(2, d0, li), enc_f(e0.z)); atomicMin(&MINS(3, d0, li), enc_f(e0.w));
        atomicMin(&MINS(0, d1, li), enc_f(e1.x)); atomicMin(&MINS(1, d1, li), enc_f(e1.y));
        atomicMin(&MINS(2, d1, li), enc_f(e1.z)); atomicMin(&MINS(3, d1, li), enc_f(e1.w));
        atomicMin(&MINS(0, d2, li), enc_f(e2.x)); atomicMin(&MINS(1, d2, li), enc_f(e2.y));
        atomicMin(&MINS(2, d2, li), enc_f(e2.z)); atomicMin(&MINS(3, d2, li), enc_f(e2.w));
        atomicMin(&MINS(0, d3, li), enc_f(e3.x)); atomicMin(&MINS(1, d3, li), enc_f(e3.y));
        atomicMin(&MINS(2, d3, li), enc_f(e3.z)); atomicMin(&MINS(3, d3, li), enc_f(e3.w));
        p += 32;
    }
    while (p < prEnd) {
        int2 c0 = cp[p];
        float a0 = verts[3 * c0.x], a1 = verts[3 * c0.x + 1], a2 = verts[3 * c0.x + 2];
        int dl = c0.y - dbase;
        float4 e;
        e.x = lrelu(bvv.x + a0 * wv0.x + a1 * wv1.x + a2 * wv2.x);
        e.y = lrelu(bvv.y + a0 * wv0.y + a1 * wv1.y + a2 * wv2.y);
        e.z = lrelu(bvv.z + a0 * wv0.z + a1 * wv1.z + a2 * wv2.z);
        e.w = lrelu(bvv.w + a0 * wv0.w + a1 * wv1.w + a2 * wv2.w);
        atomicMin(&MINS(0, dl, li), enc_f(e.x)); atomicMin(&MINS(1, dl, li), enc_f(e.y));
        atomicMin(&MINS(2, dl, li), enc_f(e.z)); atomicMin(&MINS(3, dl, li), enc_f(e.w));
        p += 8;
    }
    __syncthreads();

    float4 mxv[8];
#pragma unroll
    for (int rr = 0; rr < 8; rr++) {
        int r = rbase + rr;
        unsigned m0 = MINS(0, r, li), m1 = MINS(1, r, li);
        unsigned m2 = MINS(2, r, li), m3 = MINS(3, r, li);
        float4 xdv = bf4_to_f4(xdu[rr]);
        mxv[rr].x = degv[rr] ? (xdv.x - dec_f(m0)) : 0.f;
        mxv[rr].y = degv[rr] ? (xdv.y - dec_f(m1)) : 0.f;
        mxv[rr].z = degv[rr] ? (xdv.z - dec_f(m2)) : 0.f;
        mxv[rr].w = degv[rr] ? (xdv.w - dec_f(m3)) : 0.f;
    }
    __syncthreads();
    unsigned short* h = (unsigned short*)smem;
#pragma unroll
    for (int rr = 0; rr < 8; rr++) {
        int r = rbase + rr;
        *(ushort4*)&h[r * 264 + 4 * li] = xdu[rr];
        *(ushort4*)&h[r * 264 + 128 + 4 * li] = f4_to_bf4(mxv[rr]);
    }
    __syncthreads();

    int rt = wave;
    int m = lane & 15, q = lane >> 4;
    f32x4 acc[8];
#pragma unroll
    for (int ct = 0; ct < 8; ct++) acc[ct] = (f32x4){0.f, 0.f, 0.f, 0.f};
    for (int k0 = 0; k0 < 256; k0 += 32) {
        bf16x8 a = *(const bf16x8*)&h[(rt * 16 + m) * 264 + k0 + q * 8];
#pragma unroll
        for (int ct = 0; ct < 8; ct++) {
            bf16x8 b = *(const bf16x8*)&Wt[(ct * 16 + m) * 256 + k0 + q * 8];
            acc[ct] = __builtin_amdgcn_mfma_f32_16x16x32_bf16(a, b, acc[ct], 0, 0, 0);
        }
    }
#pragma unroll
    for (int ct = 0; ct < 8; ct++) {
        int col = ct * 16 + m;
        float bc = bias[col];
#pragma unroll
        for (int reg = 0; reg < 4; reg++) {
            int r_l = rt * 16 + q * 4 + reg;
            int row = r0 + r_l;
            if (row < n_dst) {
                float xold = bfu(h[r_l * 264 + col]);
                x_eb[(size_t)row * W + col] = f2bf(xold + lrelu(acc[ct][reg] + bc));
            }
        }
    }
}

static inline char* alignp(char* p, size_t a) {
    return (char*)(((uintptr_t)p + a - 1) & ~(uintptr_t)(a - 1));
}

extern "C" void kernel_launch(void* const* d_in, const int* in_sizes, int n_in,
                              void* d_out, int out_size, void* d_ws, size_t ws_size,
                              hipStream_t stream) {
    const float* vertices = (const float*)d_in[0];
    const float* edges    = (const float*)d_in[1];
    const float* faces    = (const float*)d_in[2];
    const int* etv_v   = (const int*)d_in[3];
    const int* etv_e   = (const int*)d_in[4];
    const int* fte_e   = (const int*)d_in[5];
    const int* fte_f   = (const int*)d_in[6];
    const int* ftf_src = (const int*)d_in[7];
    const int* ftf_dst = (const int*)d_in[8];
    const float* Wv   = (const float*)d_in[9];
    const float* bv   = (const float*)d_in[10];
    const float* We   = (const float*)d_in[11];
    const float* be   = (const float*)d_in[12];
    const float* Wf   = (const float*)d_in[13];
    const float* bf_  = (const float*)d_in[14];
    const float* Wv2e = (const float*)d_in[15];
    const float* bv2e = (const float*)d_in[16];
    const float* We2f = (const float*)d_in[17];
    const float* be2f = (const float*)d_in[18];
    const float* Wm0  = (const float*)d_in[19];
    const float* bm0  = (const float*)d_in[20];
    const float* Wm1  = (const float*)d_in[21];
    const float* bm1  = (const float*)d_in[22];

    const int NV = in_sizes[0] / 3;
    const int NE = in_sizes[1] / 12;
    const int NF = in_sizes[2] / 14;
    const int N_EV = in_sizes[3];
    const int N_FE = in_sizes[5];
    const int N_FF = in_sizes[7];
    (void)NV; (void)n_in; (void)out_size; (void)ws_size;

    const int D = NE + NF + NF;
    const int NP = N_EV + N_FE + N_FF;
    const int NB = (D + BSZ - 1) >> BSHIFT;

    // ---- ws layout ----
    char* p = (char*)d_ws;
    unsigned short* x_eb = (unsigned short*)p;  p += (size_t)NE * W * sizeof(unsigned short);
    unsigned short* f0b  = (unsigned short*)p;  p += (size_t)NF * W * sizeof(unsigned short);
    unsigned short* f1b  = (unsigned short*)p;  p += (size_t)NF * W * sizeof(unsigned short);
    p = alignp(p, 16);
    int2* pairs = (int2*)p;                     p += (size_t)NP * sizeof(int2);
    int2* cp    = (int2*)p;                     p += (size_t)NP * sizeof(int2);
    int* rowptr = (int*)p;                      p += (size_t)(D + 1) * sizeof(int);
    int* gcnt   = (int*)p;                      p += 512 * sizeof(int);
    int* goff   = (int*)p;                      p += 513 * sizeof(int);
    int* gcur   = (int*)p;                      p += 512 * sizeof(int);
    p = alignp(p, 16);
    unsigned short* Wt0 = (unsigned short*)p;   p += (size_t)32768 * sizeof(unsigned short);
    unsigned short* Wt1 = (unsigned short*)p;   p += (size_t)32768 * sizeof(unsigned short);
    unsigned short* Wt2 = (unsigned short*)p;   p += (size_t)32768 * sizeof(unsigned short);
    unsigned short* Wt3 = (unsigned short*)p;   p += (size_t)32768 * sizeof(unsigned short);

    float* out_f = (float*)d_out;
    const int TB = 256;

    // ---- embeds (bf16); x_v folded into conv1 ----
    embed_kernel<12><<<((size_t)NE * W + TB - 1) / TB, TB, 0, stream>>>(edges, We, be, x_eb, NE);
    embed_kernel<14><<<((size_t)NF * W + TB - 1) / TB, TB, 0, stream>>>(faces, Wf, bf_, f0b, NF);
    wconv4_kernel<<<512, TB, 0, stream>>>(Wv2e, We2f, Wm0, Wm1, Wt0, Wt1, Wt2, Wt3);

    // ---- bucket-partitioned CSR build ----
    PairSrc P = {etv_e, etv_v, N_EV, fte_f, fte_e, N_FE, ftf_dst, ftf_src, N_FF, NE, NF};
    (void)hipMemsetAsync(gcnt, 0, 512 * sizeof(int), stream);
    int ablocks = (NP + CHUNK - 1) / CHUNK;
    part_hist<<<ablocks, TB, 0, stream>>>(P, gcnt);
    bucket_scan<<<1, 512, 0, stream>>>(gcnt, goff, gcur, NB, NP);
    part_scatter<<<ablocks, TB, 0, stream>>>(P, gcur, pairs);
    bucket_sort<<<NB, TB, 0, stream>>>(pairs, goff, D, NP, rowptr, cp);

    // ---- fused convs ----
    fused_conv_v2e_ep<<<(NE + ROWS - 1) / ROWS, TB, 0, stream>>>(vertices, Wv, bv, x_eb, rowptr,
                                                                 cp, Wt0, bv2e, NE);
    fused_conv_ep<false><<<(NF + ROWS - 1) / ROWS, TB, 0, stream>>>(
        x_eb, f0b, f0b, nullptr, rowptr + NE, cp, NE, Wt1, be2f, NF);
    fused_conv_ep<false><<<(NF + ROWS - 1) / ROWS, TB, 0, stream>>>(
        f0b, f0b, f1b, nullptr, rowptr + NE + NF, cp, NE + NF, Wt2, bm0, NF);
    fused_conv_ep<true><<<(NF + ROWS - 1) / ROWS, TB, 0, stream>>>(
        f1b, f1b, nullptr, out_f, rowptr + NE + NF, cp, NE + NF, Wt3, bm1, NF);
}